// Round 15
// baseline (45.260 us; speedup 1.0000x reference)
//
#include <hip/hip_runtime.h>
#include <hip/hip_bf16.h>

// FFM: out[b] = x_b . w_lin + b_lin + sum_{i<j} x_i W_ij x_j
// W_ij = dot(v[i, f_j, :], v[j, f_i, :])  (symmetric)
// M = 0.5*(Wu + Wu^T), zero diag, bf16, packed in MFMA B-fragment order.
// out = x . (M x + w) + b via 16x16x32 bf16 MFMA.
// R14 = R13 + amdgpu_waves_per_eu(2): R13's launch_bounds(256,2) clamped the
//     allocator at 128 VGPR -> ~100 regs spilled (WRITE_SIZE 36.6MB, 44us).
//     waves_per_eu(2) is the explicit knob for the 256-VGPR budget.

#define FK 256   // F*K = 32*8

typedef __attribute__((ext_vector_type(8))) short bf16x8;
typedef __attribute__((ext_vector_type(4))) float f32x4v;

__device__ __forceinline__ unsigned short f2bf(float x) {
    return __builtin_bit_cast(unsigned short, __float2bfloat16(x));
}
__device__ __forceinline__ float bf2f(unsigned short h) {
    return __builtin_bit_cast(float, (unsigned int)h << 16);
}

template<int CTRL>
__device__ __forceinline__ float dppadd(float v) {
    int t = __builtin_amdgcn_update_dpp(0, __builtin_bit_cast(int, v),
                                        CTRL, 0xf, 0xf, true);
    return v + __builtin_bit_cast(float, t);
}

// Barrier that does NOT drain vmcnt: LDS-visibility only.
__device__ __forceinline__ void block_sync_novm() {
    asm volatile("s_waitcnt lgkmcnt(0)\n\ts_barrier" ::: "memory");
}

// ---------------- Kernel 1: build packed M (bf16, B-fragment order) --------
// u16 element e of mpack: i8 = e&7, l = (e>>3)&63, ct = (e>>9)&15, s = e>>13;
//   holds M[k][c] with k = s*32 + ((l>>4)&3)*8 + i8, c = ct*16 + (l&15).
// One thread -> one element (coalesced u16 store).
__global__ __launch_bounds__(256) void k_build_m(
    const float* __restrict__ v, const int* __restrict__ fidx,
    unsigned short* __restrict__ mp)
{
    __shared__ int fsh[256];
    int tid = threadIdx.x;
    fsh[tid] = fidx[tid];
    __syncthreads();

    int e  = blockIdx.x * 256 + tid;          // 65536 threads
    int i8 = e & 7;
    int l  = (e >> 3) & 63;
    int ct = (e >> 9) & 15;
    int s  = e >> 13;
    int c  = ct * 16 + (l & 15);
    int k  = s * 32 + ((l >> 4) & 3) * 8 + i8;

    float acc = 0.f;
    if (k != c) {
        int fc = fsh[c];
        int fk = fsh[k];
        const float* va = v + k * FK + fc * 8;   // v[k, f_c, :]
        const float* vb = v + c * FK + fk * 8;   // v[c, f_k, :]
#pragma unroll
        for (int j = 0; j < 8; ++j) acc += va[j] * vb[j];
        acc *= 0.5f;
    }
    mp[e] = f2bf(acc);
}

// ---------------- Kernel 2: main --------------------------------------------
// 512 blocks x 256 threads (4 waves), 128 rows/block, 4 tiles x 32 rows.
// Wave w owns cols [w*64, w*64+64); its 32 B-fragments live in registers.
// x tile: 32 rows x 256 cols bf16, row stride 512 B, 16B chunks XOR-swizzled
// by chunk ^ (row&7).

__device__ __forceinline__ void stage_tile32(unsigned short* buf,
                                             const float4* pre,
                                             int srow, int l15) {
    char* b = (char*)buf;
#pragma unroll
    for (int h = 0; h < 2; ++h) {
        int row = srow + h * 16;
#pragma unroll
        for (int j = 0; j < 4; ++j) {
            const float4 val = pre[h * 4 + j];
            unsigned long long h0 = f2bf(val.x), h1 = f2bf(val.y),
                               h2 = f2bf(val.z), h3 = f2bf(val.w);
            unsigned long long pk = h0 | (h1 << 16) | (h2 << 32) | (h3 << 48);
            int chunkB = (l15 >> 1) + 8 * j;          // 16B chunk index
            int off = row * 512 + ((chunkB ^ (row & 7)) << 4) + (l15 & 1) * 8;
            *(unsigned long long*)(b + off) = pk;
        }
    }
}

__global__ __launch_bounds__(256)
__attribute__((amdgpu_waves_per_eu(2)))
void k_main(
    const float* __restrict__ x, const float* __restrict__ w_lin,
    const float* __restrict__ b_lin, const uint4* __restrict__ mpack,
    float* __restrict__ out)
{
    __shared__ unsigned short xs[2][8192];   // 2 x 16 KB bf16 tiles (32 rows)
    __shared__ float part[2][4][32];

    const int tid = threadIdx.x;
    const int w   = tid >> 6;        // 0..3
    const int l   = tid & 63;
    const int l15 = l & 15;
    const int lg  = l >> 4;          // 0..3

    const long rowbase = (long)blockIdx.x * 128;   // 128 rows per block
    const float* xg = x + rowbase * 256;

    const int srow = w * 4 + lg;     // rows srow, srow+16 staged by this thr

    // ---- prologue: tile0 loads -> Brg (L2) -> w/b -> stage0 -> tile1 loads -
    float4 pre[8];
#pragma unroll
    for (int h = 0; h < 2; ++h)
#pragma unroll
        for (int j = 0; j < 4; ++j)
            pre[h * 4 + j] = *(const float4*)(xg + (srow + h * 16) * 256 + (l15 + 16 * j) * 4);

    bf16x8 Brg[8][4];
#pragma unroll
    for (int s = 0; s < 8; ++s)
#pragma unroll
        for (int c = 0; c < 4; ++c)
            Brg[s][c] = __builtin_bit_cast(bf16x8,
                mpack[(s * 16 + w * 4 + c) * 64 + l]);

    float wv4[4];
#pragma unroll
    for (int c = 0; c < 4; ++c)
        wv4[c] = w_lin[(w * 4 + c) * 16 + l15];
    const float bv = b_lin[0];

    stage_tile32(xs[0], pre, srow, l15);
#pragma unroll
    for (int h = 0; h < 2; ++h)
#pragma unroll
        for (int j = 0; j < 4; ++j)
            pre[h * 4 + j] = *(const float4*)(xg + (32 + srow + h * 16) * 256 + (l15 + 16 * j) * 4);
    block_sync_novm();

    for (int t = 0; t < 4; ++t) {
        const char* xsb = (const char*)xs[t & 1];

        // ---- GEMM: acc = w + X_tile(32x256) @ M(:, wave's 64 cols) ----
        f32x4v acc[2][4];
#pragma unroll
        for (int rt = 0; rt < 2; ++rt)
#pragma unroll
            for (int c = 0; c < 4; ++c)
                acc[rt][c] = f32x4v{wv4[c], wv4[c], wv4[c], wv4[c]};
#pragma unroll
        for (int s = 0; s < 8; ++s) {
            int koff = (s * 64 + lg * 16) ^ ((l15 & 7) << 4);
#pragma unroll
            for (int rt = 0; rt < 2; ++rt) {
                bf16x8 af = *(const bf16x8*)(xsb + (rt * 16 + l15) * 512 + koff);
                acc[rt][0] = __builtin_amdgcn_mfma_f32_16x16x32_bf16(af, Brg[s][0], acc[rt][0], 0, 0, 0);
                acc[rt][1] = __builtin_amdgcn_mfma_f32_16x16x32_bf16(af, Brg[s][1], acc[rt][1], 0, 0, 0);
                acc[rt][2] = __builtin_amdgcn_mfma_f32_16x16x32_bf16(af, Brg[s][2], acc[rt][2], 0, 0, 0);
                acc[rt][3] = __builtin_amdgcn_mfma_f32_16x16x32_bf16(af, Brg[s][3], acc[rt][3], 0, 0, 0);
            }
        }

        // ---- dot: p[row] = sum_{cols of wave} x[row][col] * acc ----
        // C/D layout (m89): col = ct*16 + (lane&15), row = rt*16 + (lane>>4)*4 + reg
#pragma unroll
        for (int rt = 0; rt < 2; ++rt) {
#pragma unroll
            for (int r = 0; r < 4; ++r) {
                int row = rt * 16 + lg * 4 + r;
                int sw  = (row & 7) << 4;
                float pp = 0.f;
#pragma unroll
                for (int c = 0; c < 4; ++c) {
                    int col = (w * 4 + c) * 16 + l15;
                    unsigned short h = *(const unsigned short*)(xsb + row * 512 + ((col * 2) ^ sw));
                    pp += bf2f(h) * acc[rt][c][r];
                }
                pp = dppadd<0x121>(pp); pp = dppadd<0x122>(pp);
                pp = dppadd<0x124>(pp); pp = dppadd<0x128>(pp);
                if (l15 == 0) part[t & 1][w][row] = pp;
            }
        }

        // ---- stage tile t+1 into other buffer; prefetch tile t+2 ----
        if (t < 3)
            stage_tile32(xs[(t + 1) & 1], pre, srow, l15);
        if (t < 2) {
#pragma unroll
            for (int h = 0; h < 2; ++h)
#pragma unroll
                for (int j = 0; j < 4; ++j)
                    pre[h * 4 + j] = *(const float4*)(xg + ((t + 2) * 32 + srow + h * 16) * 256 + (l15 + 16 * j) * 4);
        }
        block_sync_novm();

        // ---- out write for tile t ----
        if (tid < 32) {
            float y = part[t & 1][0][tid] + part[t & 1][1][tid] +
                      part[t & 1][2][tid] + part[t & 1][3][tid];
            out[rowbase + t * 32 + tid] = y + bv;
        }
    }
}

extern "C" void kernel_launch(void* const* d_in, const int* in_sizes, int n_in,
                              void* d_out, int out_size, void* d_ws, size_t ws_size,
                              hipStream_t stream) {
    const float* x     = (const float*)d_in[0];
    const float* w_lin = (const float*)d_in[1];
    const float* b_lin = (const float*)d_in[2];
    const float* v     = (const float*)d_in[3];
    const int*   fidx  = (const int*)d_in[4];
    float* out = (float*)d_out;
    void* mpack = d_ws;   // 128 KB

    k_build_m<<<256, 256, 0, stream>>>(v, fidx, (unsigned short*)mpack);
    k_main<<<512, 256, 0, stream>>>(x, w_lin, b_lin, (const uint4*)mpack, out);
}

// Round 16
// 23.611 us; speedup vs baseline: 1.9169x; 1.9169x over previous
//
#include <hip/hip_runtime.h>
#include <hip/hip_bf16.h>

// FFM: out[b] = x_b . w_lin + b_lin + sum_{i<j} x_i W_ij x_j
// W_ij = dot(v[i, f_j, :], v[j, f_i, :])  (symmetric)
// M = 0.5*(Wu + Wu^T), zero diag, bf16, packed in MFMA B-fragment order.
// out = x . (M x + w) + b via 16x16x32 bf16 MFMA.
// R15 = R11 k_main (no-spill 16-row/4-wave, 13.9us measured) + R13 k_build
//     (1 elem/thread, ~sub-us; R12's old k_build was the hidden 8-9us).
//     Learned R14: VGPR allocator hard-caps at 128 (waves_per_eu ignored);
//     >128-reg designs spill regardless of launch_bounds.

#define FK 256   // F*K = 32*8

typedef __attribute__((ext_vector_type(8))) short bf16x8;
typedef __attribute__((ext_vector_type(4))) float f32x4v;

__device__ __forceinline__ unsigned short f2bf(float x) {
    return __builtin_bit_cast(unsigned short, __float2bfloat16(x));
}
__device__ __forceinline__ float bf2f(unsigned short h) {
    return __builtin_bit_cast(float, (unsigned int)h << 16);
}

template<int CTRL>
__device__ __forceinline__ float dppadd(float v) {
    int t = __builtin_amdgcn_update_dpp(0, __builtin_bit_cast(int, v),
                                        CTRL, 0xf, 0xf, true);
    return v + __builtin_bit_cast(float, t);
}

// Barrier that does NOT drain vmcnt: LDS-visibility only.
__device__ __forceinline__ void block_sync_novm() {
    asm volatile("s_waitcnt lgkmcnt(0)\n\ts_barrier" ::: "memory");
}

// ---------------- Kernel 1: build packed M (bf16, B-fragment order) --------
// u16 element e of mpack: i8 = e&7, l = (e>>3)&63, ct = (e>>9)&15, s = e>>13;
//   holds M[k][c] with k = s*32 + ((l>>4)&3)*8 + i8, c = ct*16 + (l&15).
// One thread -> one element (coalesced u16 store).
__global__ __launch_bounds__(256) void k_build_m(
    const float* __restrict__ v, const int* __restrict__ fidx,
    unsigned short* __restrict__ mp)
{
    __shared__ int fsh[256];
    int tid = threadIdx.x;
    fsh[tid] = fidx[tid];
    __syncthreads();

    int e  = blockIdx.x * 256 + tid;          // 65536 threads
    int i8 = e & 7;
    int l  = (e >> 3) & 63;
    int ct = (e >> 9) & 15;
    int s  = e >> 13;
    int c  = ct * 16 + (l & 15);
    int k  = s * 32 + ((l >> 4) & 3) * 8 + i8;

    float acc = 0.f;
    if (k != c) {
        int fc = fsh[c];
        int fk = fsh[k];
        const float* va = v + k * FK + fc * 8;   // v[k, f_c, :]
        const float* vb = v + c * FK + fk * 8;   // v[c, f_k, :]
#pragma unroll
        for (int j = 0; j < 8; ++j) acc += va[j] * vb[j];
        acc *= 0.5f;
    }
    mp[e] = f2bf(acc);
}

// ---------------- Kernel 2: main --------------------------------------------
// 512 blocks x 256 threads (4 waves), 128 rows/block, 8 tiles x 16 rows.
// Wave w owns cols [w*64, w*64+64); its 32 B-fragments live in registers.
// x tile: 16 rows x 256 cols bf16, row stride 512 B, 16B chunks XOR-swizzled
// by chunk ^ (row&7).

__device__ __forceinline__ void stage_tile(unsigned short* buf,
                                           const float4* pre,
                                           int row, int l15) {
    char* b = (char*)buf;
#pragma unroll
    for (int j = 0; j < 4; ++j) {
        unsigned long long h0 = f2bf(pre[j].x), h1 = f2bf(pre[j].y),
                           h2 = f2bf(pre[j].z), h3 = f2bf(pre[j].w);
        unsigned long long pk = h0 | (h1 << 16) | (h2 << 32) | (h3 << 48);
        int chunkB = (l15 >> 1) + 8 * j;              // 16B chunk index
        int off = row * 512 + ((chunkB ^ (row & 7)) << 4) + (l15 & 1) * 8;
        *(unsigned long long*)(b + off) = pk;
    }
}

__global__ __launch_bounds__(256, 2) void k_main(
    const float* __restrict__ x, const float* __restrict__ w_lin,
    const float* __restrict__ b_lin, const uint4* __restrict__ mpack,
    float* __restrict__ out)
{
    __shared__ unsigned short xs[2][4096];   // 2 x 8 KB bf16 tiles
    __shared__ float part[2][4][16];

    const int tid = threadIdx.x;
    const int w   = tid >> 6;        // 0..3
    const int l   = tid & 63;
    const int l15 = l & 15;
    const int lg  = l >> 4;          // 0..3

    const long rowbase = (long)blockIdx.x * 128;   // 128 rows per block
    const float* xg = x + rowbase * 256;

    const int srow = w * 4 + lg;     // row this thread stages (16 thr/row)

    // ---- prologue: tile0 loads -> Brg (L2) -> w/b -> stage0 -> tile1 loads -
    float4 pre[4];
#pragma unroll
    for (int j = 0; j < 4; ++j)
        pre[j] = *(const float4*)(xg + srow * 256 + (l15 + 16 * j) * 4);

    bf16x8 Brg[8][4];
#pragma unroll
    for (int s = 0; s < 8; ++s)
#pragma unroll
        for (int c = 0; c < 4; ++c)
            Brg[s][c] = __builtin_bit_cast(bf16x8,
                mpack[(s * 16 + w * 4 + c) * 64 + l]);

    float wv4[4];
#pragma unroll
    for (int c = 0; c < 4; ++c)
        wv4[c] = w_lin[(w * 4 + c) * 16 + l15];
    const float bv = b_lin[0];

    stage_tile(xs[0], pre, srow, l15);
#pragma unroll
    for (int j = 0; j < 4; ++j)
        pre[j] = *(const float4*)(xg + (16 + srow) * 256 + (l15 + 16 * j) * 4);
    block_sync_novm();

    for (int t = 0; t < 8; ++t) {
        const char* xsb = (const char*)xs[t & 1];

        // ---- GEMM: acc = w + X_tile(16x256) @ M(:, wave's 64 cols) ----
        f32x4v acc[4];
#pragma unroll
        for (int c = 0; c < 4; ++c)
            acc[c] = f32x4v{wv4[c], wv4[c], wv4[c], wv4[c]};
#pragma unroll
        for (int s = 0; s < 8; ++s) {
            int aoff = l15 * 512 + ((s * 64 + lg * 16) ^ ((l15 & 7) << 4));
            bf16x8 af = *(const bf16x8*)(xsb + aoff);
            acc[0] = __builtin_amdgcn_mfma_f32_16x16x32_bf16(af, Brg[s][0], acc[0], 0, 0, 0);
            acc[1] = __builtin_amdgcn_mfma_f32_16x16x32_bf16(af, Brg[s][1], acc[1], 0, 0, 0);
            acc[2] = __builtin_amdgcn_mfma_f32_16x16x32_bf16(af, Brg[s][2], acc[2], 0, 0, 0);
            acc[3] = __builtin_amdgcn_mfma_f32_16x16x32_bf16(af, Brg[s][3], acc[3], 0, 0, 0);
        }

        // ---- dot: p[row] = sum_{cols of wave} x[row][col] * acc ----
        // C/D layout (m89): col = ct*16 + (lane&15), row = (lane>>4)*4 + reg
#pragma unroll
        for (int r = 0; r < 4; ++r) {
            int row = lg * 4 + r;
            int sw  = (row & 7) << 4;
            float pp = 0.f;
#pragma unroll
            for (int c = 0; c < 4; ++c) {
                int col = (w * 4 + c) * 16 + l15;
                unsigned short h = *(const unsigned short*)(xsb + row * 512 + ((col * 2) ^ sw));
                pp += bf2f(h) * acc[c][r];
            }
            pp = dppadd<0x121>(pp); pp = dppadd<0x122>(pp);
            pp = dppadd<0x124>(pp); pp = dppadd<0x128>(pp);
            if (l15 == 0) part[t & 1][w][row] = pp;
        }

        // ---- stage tile t+1 into other buffer; prefetch tile t+2 ----
        if (t < 7)
            stage_tile(xs[(t + 1) & 1], pre, srow, l15);
        if (t < 6) {
#pragma unroll
            for (int j = 0; j < 4; ++j)
                pre[j] = *(const float4*)(xg + ((t + 2) * 16 + srow) * 256 + (l15 + 16 * j) * 4);
        }
        block_sync_novm();

        // ---- out write for tile t ----
        if (tid < 16) {
            float y = part[t & 1][0][tid] + part[t & 1][1][tid] +
                      part[t & 1][2][tid] + part[t & 1][3][tid];
            out[rowbase + t * 16 + tid] = y + bv;
        }
    }
}

extern "C" void kernel_launch(void* const* d_in, const int* in_sizes, int n_in,
                              void* d_out, int out_size, void* d_ws, size_t ws_size,
                              hipStream_t stream) {
    const float* x     = (const float*)d_in[0];
    const float* w_lin = (const float*)d_in[1];
    const float* b_lin = (const float*)d_in[2];
    const float* v     = (const float*)d_in[3];
    const int*   fidx  = (const int*)d_in[4];
    float* out = (float*)d_out;
    void* mpack = d_ws;   // 128 KB

    k_build_m<<<256, 256, 0, stream>>>(v, fidx, (unsigned short*)mpack);
    k_main<<<512, 256, 0, stream>>>(x, w_lin, b_lin, (const uint4*)mpack, out);
}